// Round 1
// baseline (4246.958 us; speedup 1.0000x reference)
//
#include <hip/hip_runtime.h>

#define N_NODES 100000
#define N_EDGES 600000
#define IN_DIM  512
#define HID_DIM 256
#define OUT_DIM 128

// ---------------- count / inv ----------------
__global__ __launch_bounds__(256) void count_kernel(const int* __restrict__ dst,
                                                    float* __restrict__ cnt, int nE) {
    int i = blockIdx.x * 256 + threadIdx.x;
    if (i < nE) atomicAdd(&cnt[dst[i]], 1.0f);
}

__global__ __launch_bounds__(256) void inv_kernel(float* __restrict__ cnt, int n) {
    int i = blockIdx.x * 256 + threadIdx.x;
    if (i < n) cnt[i] = 1.0f / fmaxf(cnt[i], 1.0f);
}

// ---------------- edge scatter-add ----------------
// rows: [N_NODES, DIM]; for each edge e: agg[dst[e]] += rows[src[e]]
template <int DIM>
__global__ __launch_bounds__(256) void scatter_kernel(const float* __restrict__ rows,
                                                      const int* __restrict__ src,
                                                      const int* __restrict__ dst,
                                                      float* __restrict__ agg, int nE) {
    constexpr int TPE = DIM / 4;   // threads per edge (float4 each)
    constexpr int EPB = 256 / TPE; // edges per block
    int e = blockIdx.x * EPB + threadIdx.x / TPE;
    int lane = threadIdx.x % TPE;
    if (e >= nE) return;
    int s = src[e], d = dst[e];
    float4 v = *(const float4*)(rows + (size_t)s * DIM + lane * 4);
    float* p = agg + (size_t)d * DIM + lane * 4;
    atomicAdd(p + 0, v.x);
    atomicAdd(p + 1, v.y);
    atomicAdd(p + 2, v.z);
    atomicAdd(p + 3, v.w);
}

// ---------------- fp32 tiled GEMM with fused epilogue ----------------
// C[M,N] = A[M,K] @ B[K,N]
// MODE 0: C = AB
// MODE 1: C = relu(AB + agg*inv[r] + bias)
// MODE 2: C = AB + agg*inv[r] + bias
template <int MODE>
__global__ __launch_bounds__(256) void gemm_kernel(const float* __restrict__ A,
                                                   const float* __restrict__ B,
                                                   float* __restrict__ C,
                                                   const float* __restrict__ agg,
                                                   const float* __restrict__ inv,
                                                   const float* __restrict__ bias,
                                                   int M, int N, int K) {
    __shared__ float sA[64][17]; // +1 pad: breaks 4-way bank conflict on column reads
    __shared__ float sB[16][64];
    const int tid  = threadIdx.x;
    const int row0 = blockIdx.x * 64, col0 = blockIdx.y * 64;
    const int la_row = tid >> 2;         // tid/4 : 0..63
    const int la_k   = (tid & 3) << 2;   // 0,4,8,12
    const int lb_k   = tid >> 4;         // 0..15
    const int lb_col = (tid << 2) & 63;  // 0..60
    const int tr = (tid >> 4) << 2;      // thread row offset in tile
    const int tc = (tid & 15) << 2;      // thread col offset in tile

    float acc[4][4] = {};
    const int  ga_row = row0 + la_row;
    const bool a_ok   = ga_row < M;

    for (int k0 = 0; k0 < K; k0 += 16) {
        float4 av = make_float4(0.f, 0.f, 0.f, 0.f);
        if (a_ok) av = *(const float4*)(A + (size_t)ga_row * K + k0 + la_k);
        sA[la_row][la_k + 0] = av.x;
        sA[la_row][la_k + 1] = av.y;
        sA[la_row][la_k + 2] = av.z;
        sA[la_row][la_k + 3] = av.w;
        float4 bv = *(const float4*)(B + (size_t)(k0 + lb_k) * N + col0 + lb_col);
        *(float4*)(&sB[lb_k][lb_col]) = bv;
        __syncthreads();
#pragma unroll
        for (int kk = 0; kk < 16; kk++) {
            float4 b4 = *(float4*)(&sB[kk][tc]);
            float a0 = sA[tr + 0][kk], a1 = sA[tr + 1][kk];
            float a2 = sA[tr + 2][kk], a3 = sA[tr + 3][kk];
            acc[0][0] = fmaf(a0, b4.x, acc[0][0]);
            acc[0][1] = fmaf(a0, b4.y, acc[0][1]);
            acc[0][2] = fmaf(a0, b4.z, acc[0][2]);
            acc[0][3] = fmaf(a0, b4.w, acc[0][3]);
            acc[1][0] = fmaf(a1, b4.x, acc[1][0]);
            acc[1][1] = fmaf(a1, b4.y, acc[1][1]);
            acc[1][2] = fmaf(a1, b4.z, acc[1][2]);
            acc[1][3] = fmaf(a1, b4.w, acc[1][3]);
            acc[2][0] = fmaf(a2, b4.x, acc[2][0]);
            acc[2][1] = fmaf(a2, b4.y, acc[2][1]);
            acc[2][2] = fmaf(a2, b4.z, acc[2][2]);
            acc[2][3] = fmaf(a2, b4.w, acc[2][3]);
            acc[3][0] = fmaf(a3, b4.x, acc[3][0]);
            acc[3][1] = fmaf(a3, b4.y, acc[3][1]);
            acc[3][2] = fmaf(a3, b4.z, acc[3][2]);
            acc[3][3] = fmaf(a3, b4.w, acc[3][3]);
        }
        __syncthreads();
    }

#pragma unroll
    for (int i = 0; i < 4; i++) {
        int r = row0 + tr + i;
        if (r >= M) break;
        float4 v = make_float4(acc[i][0], acc[i][1], acc[i][2], acc[i][3]);
        if (MODE >= 1) {
            float  iv = inv[r];
            float4 g  = *(const float4*)(agg + (size_t)r * N + col0 + tc);
            float4 bb = *(const float4*)(bias + col0 + tc);
            v.x += g.x * iv + bb.x;
            v.y += g.y * iv + bb.y;
            v.z += g.z * iv + bb.z;
            v.w += g.w * iv + bb.w;
            if (MODE == 1) {
                v.x = fmaxf(v.x, 0.f);
                v.y = fmaxf(v.y, 0.f);
                v.z = fmaxf(v.z, 0.f);
                v.w = fmaxf(v.w, 0.f);
            }
        }
        *(float4*)(C + (size_t)r * N + col0 + tc) = v;
    }
}

extern "C" void kernel_launch(void* const* d_in, const int* in_sizes, int n_in,
                              void* d_out, int out_size, void* d_ws, size_t ws_size,
                              hipStream_t stream) {
    const float* x   = (const float*)d_in[0];
    const int*   ei  = (const int*)d_in[1];
    const float* Wl1 = (const float*)d_in[2];
    const float* bl1 = (const float*)d_in[3];
    const float* Wr1 = (const float*)d_in[4];
    const float* Wl2 = (const float*)d_in[5];
    const float* bl2 = (const float*)d_in[6];
    const float* Wr2 = (const float*)d_in[7];
    float*       out = (float*)d_out;

    const int* src = ei;
    const int* dst = ei + N_EDGES;

    // workspace layout (floats): B1 (xWl -> h), B2 (agg1 -> hWl), B3 (agg2), cnt
    const size_t NB1 = (size_t)N_NODES * HID_DIM; // 25.6M
    const size_t NB2 = (size_t)N_NODES * HID_DIM; // 25.6M
    const size_t NB3 = (size_t)N_NODES * OUT_DIM; // 12.8M
    float* B1  = (float*)d_ws;
    float* B2  = B1 + NB1;
    float* B3  = B2 + NB2;
    float* cnt = B3 + NB3;

    // ---- degree counts + reciprocal (shared by both layers) ----
    hipMemsetAsync(cnt, 0, N_NODES * sizeof(float), stream);
    hipMemsetAsync(B2, 0, NB2 * sizeof(float), stream); // agg1 = 0
    count_kernel<<<(N_EDGES + 255) / 256, 256, 0, stream>>>(dst, cnt, N_EDGES);
    inv_kernel<<<(N_NODES + 255) / 256, 256, 0, stream>>>(cnt, N_NODES);

    const int MB = (N_NODES + 63) / 64; // 1563

    // ---- layer 1 ----
    // xWl = x @ W_l1
    gemm_kernel<0><<<dim3(MB, HID_DIM / 64), 256, 0, stream>>>(
        x, Wl1, B1, nullptr, nullptr, nullptr, N_NODES, HID_DIM, IN_DIM);
    // agg1 += xWl[src] at dst
    scatter_kernel<HID_DIM><<<N_EDGES / (256 / (HID_DIM / 4)), 256, 0, stream>>>(
        B1, src, dst, B2, N_EDGES);
    // h = relu(x @ W_r1 + agg1*inv + b_l1)   (h overwrites B1; safe, gemm reads x)
    gemm_kernel<1><<<dim3(MB, HID_DIM / 64), 256, 0, stream>>>(
        x, Wr1, B1, B2, cnt, bl1, N_NODES, HID_DIM, IN_DIM);

    // ---- layer 2 ----
    // hWl = h @ W_l2   (hWl overwrites B2; agg1 consumed above)
    gemm_kernel<0><<<dim3(MB, OUT_DIM / 64), 256, 0, stream>>>(
        B1, Wl2, B2, nullptr, nullptr, nullptr, N_NODES, OUT_DIM, HID_DIM);
    hipMemsetAsync(B3, 0, NB3 * sizeof(float), stream); // agg2 = 0
    scatter_kernel<OUT_DIM><<<N_EDGES / (256 / (OUT_DIM / 4)), 256, 0, stream>>>(
        B2, src, dst, B3, N_EDGES);
    // out = h @ W_r2 + agg2*inv + b_l2
    gemm_kernel<2><<<dim3(MB, OUT_DIM / 64), 256, 0, stream>>>(
        B1, Wr2, out, B3, cnt, bl2, N_NODES, OUT_DIM, HID_DIM);
}

// Round 2
// 1686.560 us; speedup vs baseline: 2.5181x; 2.5181x over previous
//
#include <hip/hip_runtime.h>

#define N_NODES 100000
#define N_EDGES 600000
#define IN_DIM  512
#define HID_DIM 256
#define OUT_DIM 128

// ---------------- degree count (int) ----------------
__global__ __launch_bounds__(256) void count_kernel(const int* __restrict__ dst,
                                                    int* __restrict__ cnt, int nE) {
    int i = blockIdx.x * 256 + threadIdx.x;
    if (i < nE) atomicAdd(&cnt[dst[i]], 1);
}

// ---------------- single-block exclusive scan over N_NODES counts ----------------
// writes rowptr[0..n], cursor[0..n-1] (= rowptr), inv[0..n-1] = 1/max(cnt,1)
__global__ __launch_bounds__(1024) void scan_kernel(const int* __restrict__ cnt,
                                                    int* __restrict__ rowptr,
                                                    int* __restrict__ cursor,
                                                    float* __restrict__ inv, int n) {
    __shared__ int ssum[1024];
    const int t = threadIdx.x;
    const int PER = (n + 1023) / 1024;
    const int begin = t * PER;
    const int end   = min(begin + PER, n);
    int sum = 0;
    for (int i = begin; i < end; i++) sum += cnt[i];
    ssum[t] = sum;
    __syncthreads();
    // Hillis-Steele inclusive scan
    for (int off = 1; off < 1024; off <<= 1) {
        int add = (t >= off) ? ssum[t - off] : 0;
        __syncthreads();
        ssum[t] += add;
        __syncthreads();
    }
    int run = ssum[t] - sum; // exclusive prefix of this thread's chunk
    for (int i = begin; i < end; i++) {
        int c = cnt[i];
        rowptr[i] = run;
        cursor[i] = run;
        inv[i]    = 1.0f / (float)max(c, 1);
        run += c;
    }
    if (t == 1023) rowptr[n] = ssum[1023];
}

// ---------------- CSR fill: col[pos] = src for each in-edge of dst ----------------
__global__ __launch_bounds__(256) void fill_kernel(const int* __restrict__ src,
                                                   const int* __restrict__ dst,
                                                   int* __restrict__ cursor,
                                                   int* __restrict__ col, int nE) {
    int e = blockIdx.x * 256 + threadIdx.x;
    if (e < nE) {
        int pos = atomicAdd(&cursor[dst[e]], 1);
        col[pos] = src[e];
    }
}

// ---------------- pull-based aggregation: agg[d] = sum_{e in-edges(d)} rows[col[e]] ----------------
// one wave (64 lanes) per node; DIM/64 floats per lane
template <int DIM>
__global__ __launch_bounds__(256) void agg_kernel(const float* __restrict__ rows,
                                                  const int* __restrict__ rowptr,
                                                  const int* __restrict__ col,
                                                  float* __restrict__ agg, int n) {
    constexpr int VF = DIM / 64; // 4 or 2
    const int node = blockIdx.x * 4 + (threadIdx.x >> 6);
    const int lane = threadIdx.x & 63;
    if (node >= n) return;
    const int e0 = rowptr[node], e1 = rowptr[node + 1];
    if constexpr (VF == 4) {
        float4 acc = make_float4(0.f, 0.f, 0.f, 0.f);
        int e = e0;
        for (; e + 1 < e1; e += 2) { // unroll-2: two independent gather loads in flight
            int s0 = col[e], s1 = col[e + 1];
            float4 v0 = *(const float4*)(rows + (size_t)s0 * DIM + lane * 4);
            float4 v1 = *(const float4*)(rows + (size_t)s1 * DIM + lane * 4);
            acc.x += v0.x + v1.x; acc.y += v0.y + v1.y;
            acc.z += v0.z + v1.z; acc.w += v0.w + v1.w;
        }
        if (e < e1) {
            int s0 = col[e];
            float4 v0 = *(const float4*)(rows + (size_t)s0 * DIM + lane * 4);
            acc.x += v0.x; acc.y += v0.y; acc.z += v0.z; acc.w += v0.w;
        }
        *(float4*)(agg + (size_t)node * DIM + lane * 4) = acc;
    } else {
        float2 acc = make_float2(0.f, 0.f);
        int e = e0;
        for (; e + 1 < e1; e += 2) {
            int s0 = col[e], s1 = col[e + 1];
            float2 v0 = *(const float2*)(rows + (size_t)s0 * DIM + lane * 2);
            float2 v1 = *(const float2*)(rows + (size_t)s1 * DIM + lane * 2);
            acc.x += v0.x + v1.x; acc.y += v0.y + v1.y;
        }
        if (e < e1) {
            int s0 = col[e];
            float2 v0 = *(const float2*)(rows + (size_t)s0 * DIM + lane * 2);
            acc.x += v0.x; acc.y += v0.y;
        }
        *(float2*)(agg + (size_t)node * DIM + lane * 2) = acc;
    }
}

// ---------------- fp32 tiled GEMM with fused epilogue ----------------
// C[M,N] = A[M,K] @ B[K,N]
// MODE 0: C = AB ; MODE 1: C = relu(AB + agg*inv[r] + bias) ; MODE 2: no relu
template <int MODE>
__global__ __launch_bounds__(256) void gemm_kernel(const float* __restrict__ A,
                                                   const float* __restrict__ B,
                                                   float* __restrict__ C,
                                                   const float* __restrict__ agg,
                                                   const float* __restrict__ inv,
                                                   const float* __restrict__ bias,
                                                   int M, int N, int K) {
    __shared__ float sA[64][17];
    __shared__ float sB[16][64];
    const int tid  = threadIdx.x;
    const int row0 = blockIdx.x * 64, col0 = blockIdx.y * 64;
    const int la_row = tid >> 2;
    const int la_k   = (tid & 3) << 2;
    const int lb_k   = tid >> 4;
    const int lb_col = (tid << 2) & 63;
    const int tr = (tid >> 4) << 2;
    const int tc = (tid & 15) << 2;

    float acc[4][4] = {};
    const int  ga_row = row0 + la_row;
    const bool a_ok   = ga_row < M;

    for (int k0 = 0; k0 < K; k0 += 16) {
        float4 av = make_float4(0.f, 0.f, 0.f, 0.f);
        if (a_ok) av = *(const float4*)(A + (size_t)ga_row * K + k0 + la_k);
        sA[la_row][la_k + 0] = av.x;
        sA[la_row][la_k + 1] = av.y;
        sA[la_row][la_k + 2] = av.z;
        sA[la_row][la_k + 3] = av.w;
        float4 bv = *(const float4*)(B + (size_t)(k0 + lb_k) * N + col0 + lb_col);
        *(float4*)(&sB[lb_k][lb_col]) = bv;
        __syncthreads();
#pragma unroll
        for (int kk = 0; kk < 16; kk++) {
            float4 b4 = *(float4*)(&sB[kk][tc]);
            float a0 = sA[tr + 0][kk], a1 = sA[tr + 1][kk];
            float a2 = sA[tr + 2][kk], a3 = sA[tr + 3][kk];
            acc[0][0] = fmaf(a0, b4.x, acc[0][0]);
            acc[0][1] = fmaf(a0, b4.y, acc[0][1]);
            acc[0][2] = fmaf(a0, b4.z, acc[0][2]);
            acc[0][3] = fmaf(a0, b4.w, acc[0][3]);
            acc[1][0] = fmaf(a1, b4.x, acc[1][0]);
            acc[1][1] = fmaf(a1, b4.y, acc[1][1]);
            acc[1][2] = fmaf(a1, b4.z, acc[1][2]);
            acc[1][3] = fmaf(a1, b4.w, acc[1][3]);
            acc[2][0] = fmaf(a2, b4.x, acc[2][0]);
            acc[2][1] = fmaf(a2, b4.y, acc[2][1]);
            acc[2][2] = fmaf(a2, b4.z, acc[2][2]);
            acc[2][3] = fmaf(a2, b4.w, acc[2][3]);
            acc[3][0] = fmaf(a3, b4.x, acc[3][0]);
            acc[3][1] = fmaf(a3, b4.y, acc[3][1]);
            acc[3][2] = fmaf(a3, b4.z, acc[3][2]);
            acc[3][3] = fmaf(a3, b4.w, acc[3][3]);
        }
        __syncthreads();
    }

#pragma unroll
    for (int i = 0; i < 4; i++) {
        int r = row0 + tr + i;
        if (r >= M) break;
        float4 v = make_float4(acc[i][0], acc[i][1], acc[i][2], acc[i][3]);
        if (MODE >= 1) {
            float  iv = inv[r];
            float4 g  = *(const float4*)(agg + (size_t)r * N + col0 + tc);
            float4 bb = *(const float4*)(bias + col0 + tc);
            v.x += g.x * iv + bb.x;
            v.y += g.y * iv + bb.y;
            v.z += g.z * iv + bb.z;
            v.w += g.w * iv + bb.w;
            if (MODE == 1) {
                v.x = fmaxf(v.x, 0.f);
                v.y = fmaxf(v.y, 0.f);
                v.z = fmaxf(v.z, 0.f);
                v.w = fmaxf(v.w, 0.f);
            }
        }
        *(float4*)(C + (size_t)r * N + col0 + tc) = v;
    }
}

extern "C" void kernel_launch(void* const* d_in, const int* in_sizes, int n_in,
                              void* d_out, int out_size, void* d_ws, size_t ws_size,
                              hipStream_t stream) {
    const float* x   = (const float*)d_in[0];
    const int*   ei  = (const int*)d_in[1];
    const float* Wl1 = (const float*)d_in[2];
    const float* bl1 = (const float*)d_in[3];
    const float* Wr1 = (const float*)d_in[4];
    const float* Wl2 = (const float*)d_in[5];
    const float* bl2 = (const float*)d_in[6];
    const float* Wr2 = (const float*)d_in[7];
    float*       out = (float*)d_out;

    const int* src = ei;
    const int* dst = ei + N_EDGES;

    // workspace layout
    const size_t NB1 = (size_t)N_NODES * HID_DIM; // 25.6M floats
    const size_t NB2 = (size_t)N_NODES * HID_DIM;
    const size_t NB3 = (size_t)N_NODES * OUT_DIM; // 12.8M floats
    float* B1     = (float*)d_ws;
    float* B2     = B1 + NB1;
    float* B3     = B2 + NB2;
    float* inv    = B3 + NB3;                 // N_NODES floats
    int*   cnt    = (int*)(inv + N_NODES);    // N_NODES
    int*   rowptr = cnt + N_NODES;            // N_NODES+1
    int*   cursor = rowptr + N_NODES + 1;     // N_NODES
    int*   col    = cursor + N_NODES;         // N_EDGES

    // ---- CSR build (shared by both layers) ----
    hipMemsetAsync(cnt, 0, N_NODES * sizeof(int), stream);
    count_kernel<<<(N_EDGES + 255) / 256, 256, 0, stream>>>(dst, cnt, N_EDGES);
    scan_kernel<<<1, 1024, 0, stream>>>(cnt, rowptr, cursor, inv, N_NODES);
    fill_kernel<<<(N_EDGES + 255) / 256, 256, 0, stream>>>(src, dst, cursor, col, N_EDGES);

    const int MB = (N_NODES + 63) / 64; // 1563
    const int AB = N_NODES / 4;         // 25000 agg blocks (4 waves/block)

    // ---- layer 1 ----
    gemm_kernel<0><<<dim3(MB, HID_DIM / 64), 256, 0, stream>>>(
        x, Wl1, B1, nullptr, nullptr, nullptr, N_NODES, HID_DIM, IN_DIM);
    agg_kernel<HID_DIM><<<AB, 256, 0, stream>>>(B1, rowptr, col, B2, N_NODES);
    gemm_kernel<1><<<dim3(MB, HID_DIM / 64), 256, 0, stream>>>(
        x, Wr1, B1, B2, inv, bl1, N_NODES, HID_DIM, IN_DIM);

    // ---- layer 2 ----
    gemm_kernel<0><<<dim3(MB, OUT_DIM / 64), 256, 0, stream>>>(
        B1, Wl2, B2, nullptr, nullptr, nullptr, N_NODES, OUT_DIM, HID_DIM);
    agg_kernel<OUT_DIM><<<AB, 256, 0, stream>>>(B2, rowptr, col, B3, N_NODES);
    gemm_kernel<2><<<dim3(MB, OUT_DIM / 64), 256, 0, stream>>>(
        B1, Wr2, out, B3, inv, bl2, N_NODES, OUT_DIM, HID_DIM);
}

// Round 3
// 1091.121 us; speedup vs baseline: 3.8923x; 1.5457x over previous
//
#include <hip/hip_runtime.h>

#define N_NODES 100000
#define N_EDGES 600000
#define IN_DIM  512
#define HID_DIM 256
#define OUT_DIM 128

typedef unsigned short u16;
typedef unsigned int   u32;
typedef __attribute__((ext_vector_type(8))) short bf16x8;
typedef __attribute__((ext_vector_type(4))) float f32x4;

__device__ __forceinline__ u16 f2bf(float f) {
    u32 u = __float_as_uint(f);
    return (u16)((u + 0x7FFFu + ((u >> 16) & 1u)) >> 16); // round-to-nearest-even
}
__device__ __forceinline__ float bf2f(u16 b) { return __uint_as_float((u32)b << 16); }
__device__ __forceinline__ float lo16f(u32 u) { return __uint_as_float(u << 16); }
__device__ __forceinline__ float hi16f(u32 u) { return __uint_as_float(u & 0xFFFF0000u); }

// async global->LDS, 16B per lane; dest = wave-uniform base + lane*16
#define GLD16(g, l) __builtin_amdgcn_global_load_lds( \
    (const __attribute__((address_space(1))) void*)(g), \
    (__attribute__((address_space(3))) void*)(l), 16, 0, 0)

// ---------------- CSR build ----------------
__global__ __launch_bounds__(256) void count_kernel(const int* __restrict__ dst,
                                                    int* __restrict__ cnt, int nE) {
    int i = blockIdx.x * 256 + threadIdx.x;
    if (i < nE) atomicAdd(&cnt[dst[i]], 1);
}

__global__ __launch_bounds__(1024) void scan_kernel(const int* __restrict__ cnt,
                                                    int* __restrict__ rowptr,
                                                    int* __restrict__ cursor,
                                                    float* __restrict__ inv, int n) {
    __shared__ int ssum[1024];
    const int t = threadIdx.x;
    const int PER = (n + 1023) / 1024;
    const int begin = t * PER;
    const int end   = min(begin + PER, n);
    int sum = 0;
    for (int i = begin; i < end; i++) sum += cnt[i];
    ssum[t] = sum;
    __syncthreads();
    for (int off = 1; off < 1024; off <<= 1) {
        int add = (t >= off) ? ssum[t - off] : 0;
        __syncthreads();
        ssum[t] += add;
        __syncthreads();
    }
    int run = ssum[t] - sum;
    for (int i = begin; i < end; i++) {
        int c = cnt[i];
        rowptr[i] = run;
        cursor[i] = run;
        inv[i]    = 1.0f / (float)max(c, 1);
        run += c;
    }
    if (t == 1023) rowptr[n] = ssum[1023];
}

__global__ __launch_bounds__(256) void fill_kernel(const int* __restrict__ src,
                                                   const int* __restrict__ dst,
                                                   int* __restrict__ cursor,
                                                   int* __restrict__ col, int nE) {
    int e = blockIdx.x * 256 + threadIdx.x;
    if (e < nE) {
        int pos = atomicAdd(&cursor[dst[e]], 1);
        col[pos] = src[e];
    }
}

// ---------------- conversions ----------------
__global__ __launch_bounds__(256) void cvt_x_kernel(const float4* __restrict__ x,
                                                    uint2* __restrict__ xb, int n4) {
    int stride = gridDim.x * 256;
    for (int i = blockIdx.x * 256 + threadIdx.x; i < n4; i += stride) {
        float4 v = x[i];
        uint2 o;
        o.x = (u32)f2bf(v.x) | ((u32)f2bf(v.y) << 16);
        o.y = (u32)f2bf(v.z) | ((u32)f2bf(v.w) << 16);
        xb[i] = o;
    }
}

// W [K,N] fp32 row-major -> transposed bf16 hi/lo [N,K]
__global__ __launch_bounds__(256) void cvt_w_kernel(const float* __restrict__ W,
                                                    u16* __restrict__ Thi,
                                                    u16* __restrict__ Tlo, int K, int N) {
    int i = blockIdx.x * 256 + threadIdx.x;
    if (i >= K * N) return;
    int k = i / N, n = i % N;
    float w = W[i];
    u16 h = f2bf(w);
    u16 l = f2bf(w - bf2f(h));
    Thi[(size_t)n * K + k] = h;
    Tlo[(size_t)n * K + k] = l;
}

// ---------------- bf16 MFMA GEMM: C[M,N] = A @ (Bhi+Blo)^T, fused epilogue ----------------
// A [M,K] bf16; Bhi/Blo [N,K] bf16.
// MODE 0: C = bf16(AB)
// MODE 1: C = bf16(relu(AB + agg + bias))   (agg already inv-scaled)
// MODE 2: C = fp32(AB + agg + bias)
template <int MODE, int N, int K>
__global__ __launch_bounds__(256) void gemm_bf(const u16* __restrict__ A,
                                               const u16* __restrict__ Bhi,
                                               const u16* __restrict__ Blo,
                                               void* __restrict__ Cout,
                                               const u16* __restrict__ agg,
                                               const float* __restrict__ bias,
                                               int M) {
    // 24 KB LDS, [kchunk(4)][row/col(128)][8 bf16] per region: A | Bhi | Blo
    __shared__ u16 lds[12288];
    const int tid  = threadIdx.x;
    const int wave = tid >> 6, lane = tid & 63;
    const int wm = wave >> 1, wn = wave & 1;
    const int row0 = blockIdx.x * 128, col0 = blockIdx.y * 128;
    const int kcl = lane >> 4, rl = lane & 15;

    f32x4 acc[4][4] = {};

    for (int k0 = 0; k0 < K; k0 += 32) {
        // stage A (8KB) + Bhi (8KB) + Blo (8KB): 6 rounds x 256 thr x 16B
#pragma unroll
        for (int rr = 0; rr < 6; rr++) {
            const int region = rr >> 1;              // 0=A 1=Bhi 2=Blo (compile-time)
            const int ls  = ((rr & 1) << 2) + wave;  // local 1KB slot 0..7 (wave-uniform)
            const int u   = (ls << 6) + lane;        // 16B-unit index 0..511
            const int kc  = u >> 7, idx = u & 127;
            const u16* src;
            if (region == 0)      src = A   + (size_t)min(row0 + idx, M - 1) * K + k0 + kc * 8;
            else if (region == 1) src = Bhi + (size_t)(col0 + idx) * K + k0 + kc * 8;
            else                  src = Blo + (size_t)(col0 + idx) * K + k0 + kc * 8;
            GLD16(src, &lds[region * 4096 + ls * 512]);
        }
        __syncthreads();

        const bf16x8* L = (const bf16x8*)lds; // 16B units
        bf16x8 a[4], bh[4], bl[4];
#pragma unroll
        for (int m = 0; m < 4; m++) a[m] = L[kcl * 128 + wm * 64 + m * 16 + rl];
#pragma unroll
        for (int n = 0; n < 4; n++) {
            bh[n] = L[512  + kcl * 128 + wn * 64 + n * 16 + rl];
            bl[n] = L[1024 + kcl * 128 + wn * 64 + n * 16 + rl];
        }
#pragma unroll
        for (int m = 0; m < 4; m++)
#pragma unroll
            for (int n = 0; n < 4; n++) {
                acc[m][n] = __builtin_amdgcn_mfma_f32_16x16x32_bf16(a[m], bh[n], acc[m][n], 0, 0, 0);
                acc[m][n] = __builtin_amdgcn_mfma_f32_16x16x32_bf16(a[m], bl[n], acc[m][n], 0, 0, 0);
            }
        __syncthreads();
    }

    // epilogue: C/D layout col=lane&15, row=(lane>>4)*4+reg
    const int rbase = row0 + wm * 64 + kcl * 4;
    const int cbase = col0 + wn * 64 + rl;
#pragma unroll
    for (int m = 0; m < 4; m++) {
#pragma unroll
        for (int n = 0; n < 4; n++) {
            const int c = cbase + n * 16;
            float bs = 0.f;
            if (MODE >= 1) bs = bias[c];
#pragma unroll
            for (int j = 0; j < 4; j++) {
                const int r = rbase + m * 16 + j;
                if (r < M) {
                    float v = acc[m][n][j];
                    if (MODE >= 1) {
                        v += bf2f(agg[(size_t)r * N + c]) + bs;
                        if (MODE == 1) v = fmaxf(v, 0.f);
                    }
                    if (MODE == 2) ((float*)Cout)[(size_t)r * N + c] = v;
                    else           ((u16*)Cout)[(size_t)r * N + c]  = f2bf(v);
                }
            }
        }
    }
}

// ---------------- pull aggregation over bf16 rows, fp32 acc, inv-scaled bf16 out ----------------
template <int DIM>
__global__ __launch_bounds__(256) void agg_bf(const u16* __restrict__ rows,
                                              const int* __restrict__ rowptr,
                                              const int* __restrict__ col,
                                              const float* __restrict__ inv,
                                              u16* __restrict__ aggo, int n) {
    constexpr int LPN = DIM / 4;   // lanes per node (4 bf16 per lane)
    constexpr int NPB = 256 / LPN; // nodes per block
    const int node = blockIdx.x * NPB + threadIdx.x / LPN;
    const int lane = threadIdx.x % LPN;
    if (node >= n) return;
    const int e0 = rowptr[node], e1 = rowptr[node + 1];
    const size_t lo = (size_t)lane * 4;
    float a0 = 0.f, a1 = 0.f, a2 = 0.f, a3 = 0.f;
    int e = e0;
    for (; e + 1 < e1; e += 2) {
        int s0 = col[e], s1 = col[e + 1];
        uint2 v0 = *(const uint2*)(rows + (size_t)s0 * DIM + lo);
        uint2 v1 = *(const uint2*)(rows + (size_t)s1 * DIM + lo);
        a0 += lo16f(v0.x) + lo16f(v1.x);
        a1 += hi16f(v0.x) + hi16f(v1.x);
        a2 += lo16f(v0.y) + lo16f(v1.y);
        a3 += hi16f(v0.y) + hi16f(v1.y);
    }
    if (e < e1) {
        int s0 = col[e];
        uint2 v0 = *(const uint2*)(rows + (size_t)s0 * DIM + lo);
        a0 += lo16f(v0.x); a1 += hi16f(v0.x);
        a2 += lo16f(v0.y); a3 += hi16f(v0.y);
    }
    const float iv = inv[node];
    uint2 o;
    o.x = (u32)f2bf(a0 * iv) | ((u32)f2bf(a1 * iv) << 16);
    o.y = (u32)f2bf(a2 * iv) | ((u32)f2bf(a3 * iv) << 16);
    *(uint2*)(aggo + (size_t)node * DIM + lo) = o;
}

extern "C" void kernel_launch(void* const* d_in, const int* in_sizes, int n_in,
                              void* d_out, int out_size, void* d_ws, size_t ws_size,
                              hipStream_t stream) {
    const float* x   = (const float*)d_in[0];
    const int*   ei  = (const int*)d_in[1];
    const float* Wl1 = (const float*)d_in[2];
    const float* bl1 = (const float*)d_in[3];
    const float* Wr1 = (const float*)d_in[4];
    const float* Wl2 = (const float*)d_in[5];
    const float* bl2 = (const float*)d_in[6];
    const float* Wr2 = (const float*)d_in[7];
    float*       out = (float*)d_out;

    const int* src = ei;
    const int* dst = ei + N_EDGES;

    // ---- workspace layout (~210 MB) ----
    u16* xbf   = (u16*)d_ws;            // [N,512] bf16           (102.4 MB)
    u16* Cbuf  = xbf + 51200000;        // xWl_bf, then h_bf      (51.2 MB)
    u16* Dbuf  = Cbuf + 25600000;       // agg1; then hWl+agg2    (51.2 MB)
    u16* Wl1hi = Dbuf + 25600000;
    u16* Wl1lo = Wl1hi + 131072;
    u16* Wr1hi = Wl1lo + 131072;
    u16* Wr1lo = Wr1hi + 131072;
    u16* Wl2hi = Wr1lo + 131072;
    u16* Wl2lo = Wl2hi + 32768;
    u16* Wr2hi = Wl2lo + 32768;
    u16* Wr2lo = Wr2hi + 32768;
    float* inv   = (float*)(Wr2lo + 32768);
    int*  cnt    = (int*)(inv + N_NODES);
    int*  rowptr = cnt + N_NODES;
    int*  cursor = rowptr + N_NODES + 1;
    int*  colw   = cursor + N_NODES;

    u16* xwl  = Cbuf;               // layer1 transformed msgs
    u16* hbf  = Cbuf;               // h overwrites xwl (dead after agg1)
    u16* agg1 = Dbuf;
    u16* hwl  = Dbuf;               // overwrites agg1 (dead after G1b)
    u16* agg2 = Dbuf + 12800000;

    // ---- CSR build ----
    hipMemsetAsync(cnt, 0, N_NODES * sizeof(int), stream);
    count_kernel<<<(N_EDGES + 255) / 256, 256, 0, stream>>>(dst, cnt, N_EDGES);
    scan_kernel<<<1, 1024, 0, stream>>>(cnt, rowptr, cursor, inv, N_NODES);
    fill_kernel<<<(N_EDGES + 255) / 256, 256, 0, stream>>>(src, dst, cursor, colw, N_EDGES);

    // ---- conversions ----
    cvt_x_kernel<<<4096, 256, 0, stream>>>((const float4*)x, (uint2*)xbf,
                                           N_NODES * IN_DIM / 4);
    cvt_w_kernel<<<(IN_DIM * HID_DIM + 255) / 256, 256, 0, stream>>>(Wl1, Wl1hi, Wl1lo, IN_DIM, HID_DIM);
    cvt_w_kernel<<<(IN_DIM * HID_DIM + 255) / 256, 256, 0, stream>>>(Wr1, Wr1hi, Wr1lo, IN_DIM, HID_DIM);
    cvt_w_kernel<<<(HID_DIM * OUT_DIM + 255) / 256, 256, 0, stream>>>(Wl2, Wl2hi, Wl2lo, HID_DIM, OUT_DIM);
    cvt_w_kernel<<<(HID_DIM * OUT_DIM + 255) / 256, 256, 0, stream>>>(Wr2, Wr2hi, Wr2lo, HID_DIM, OUT_DIM);

    const int MB = (N_NODES + 127) / 128; // 782

    // ---- layer 1 ----
    gemm_bf<0, HID_DIM, IN_DIM><<<dim3(MB, HID_DIM / 128), 256, 0, stream>>>(
        xbf, Wl1hi, Wl1lo, xwl, nullptr, nullptr, N_NODES);
    agg_bf<HID_DIM><<<N_NODES / 4, 256, 0, stream>>>(xwl, rowptr, colw, inv, agg1, N_NODES);
    gemm_bf<1, HID_DIM, IN_DIM><<<dim3(MB, HID_DIM / 128), 256, 0, stream>>>(
        xbf, Wr1hi, Wr1lo, hbf, agg1, bl1, N_NODES);

    // ---- layer 2 ----
    gemm_bf<0, OUT_DIM, HID_DIM><<<dim3(MB, OUT_DIM / 128), 256, 0, stream>>>(
        hbf, Wl2hi, Wl2lo, hwl, nullptr, nullptr, N_NODES);
    agg_bf<OUT_DIM><<<N_NODES / 8, 256, 0, stream>>>(hwl, rowptr, colw, inv, agg2, N_NODES);
    gemm_bf<2, OUT_DIM, HID_DIM><<<dim3(MB, OUT_DIM / 128), 256, 0, stream>>>(
        hbf, Wr2hi, Wr2lo, out, agg2, bl2, N_NODES);
}